// Round 1
// baseline (3397.631 us; speedup 1.0000x reference)
//
#include <hip/hip_runtime.h>

#define N_NODES 100000
#define N_EDGES 3200000
#define NUM_FEATURES 128
#define DIM 10
#define NUM_GRAPHS 64

// ---------------------------------------------------------------------------
// Kernel A: h1 = features @ W1   [100000,128] x [128,10]
// 32 lanes per node; lane l owns W1 rows 4l..4l+3 in registers; float4 feature
// loads are fully coalesced (half-wave reads one contiguous 512B row).
// ---------------------------------------------------------------------------
__global__ __launch_bounds__(256) void k_gemm_w1(const float* __restrict__ feat,
                                                 const float* __restrict__ W1,
                                                 float* __restrict__ h1) {
    int gid  = blockIdx.x * blockDim.x + threadIdx.x;
    int node = gid >> 5;
    int lane = gid & 31;
    if (node >= N_NODES) return;

    float w[4][DIM];
#pragma unroll
    for (int j = 0; j < 4; ++j)
#pragma unroll
        for (int k = 0; k < DIM; ++k)
            w[j][k] = W1[(lane * 4 + j) * DIM + k];   // L1-resident (5 KB)

    const float4 f = *reinterpret_cast<const float4*>(feat + (size_t)node * NUM_FEATURES + lane * 4);
    float fv[4] = {f.x, f.y, f.z, f.w};

    float acc[DIM];
#pragma unroll
    for (int k = 0; k < DIM; ++k) acc[k] = 0.f;
#pragma unroll
    for (int j = 0; j < 4; ++j)
#pragma unroll
        for (int k = 0; k < DIM; ++k)
            acc[k] += fv[j] * w[j][k];

    // butterfly reduce across the 32-lane group (xor<32 stays in-group on wave64)
#pragma unroll
    for (int off = 16; off > 0; off >>= 1)
#pragma unroll
        for (int k = 0; k < DIM; ++k)
            acc[k] += __shfl_xor(acc[k], off);

    if (lane == 0) {
#pragma unroll
        for (int k = 0; k < DIM; ++k) h1[node * DIM + k] = acc[k];
    }
}

// ---------------------------------------------------------------------------
// Kernel B/C: out[dst[e]] += (RELU ? relu(h[src[e]]) : h[src[e]])
// one thread per edge, 10 f32 atomics. h is 4 MB -> gathers hit L2/LLC.
// ---------------------------------------------------------------------------
template <int RELU>
__global__ __launch_bounds__(256) void k_edge_scatter(const float* __restrict__ h,
                                                      const int* __restrict__ src,
                                                      const int* __restrict__ dst,
                                                      float* __restrict__ out) {
    int e = blockIdx.x * blockDim.x + threadIdx.x;
    if (e >= N_EDGES) return;
    int s = src[e];
    int d = dst[e];

    const float2* hp = reinterpret_cast<const float2*>(h + (size_t)s * DIM);  // 8B-aligned
    float v[DIM];
#pragma unroll
    for (int j = 0; j < 5; ++j) {
        float2 t  = hp[j];
        v[2 * j]     = t.x;
        v[2 * j + 1] = t.y;
    }
    if (RELU) {
#pragma unroll
        for (int k = 0; k < DIM; ++k) v[k] = fmaxf(v[k], 0.f);
    }
    float* op = out + (size_t)d * DIM;
#pragma unroll
    for (int k = 0; k < DIM; ++k) atomicAdd(op + k, v[k]);
}

// ---------------------------------------------------------------------------
// Kernel D: per-graph sums of agg2 + node counts. graph_ids is SORTED, so
// almost every wave is graph-uniform -> butterfly reduce + 10 atomics/wave.
// ---------------------------------------------------------------------------
__global__ __launch_bounds__(256) void k_pool(const float* __restrict__ agg2,
                                              const int* __restrict__ gids,
                                              float* __restrict__ sums,
                                              float* __restrict__ cnt) {
    int n      = blockIdx.x * blockDim.x + threadIdx.x;
    bool valid = (n < N_NODES);
    int g      = valid ? gids[n] : -1;

    float v[DIM];
#pragma unroll
    for (int k = 0; k < DIM; ++k)
        v[k] = valid ? agg2[(size_t)n * DIM + k] : 0.f;

    int  g0  = __shfl(g, 0);
    bool uni = __all(g == g0);

    if (uni && g0 >= 0) {  // whole wave valid + same graph
#pragma unroll
        for (int off = 32; off > 0; off >>= 1)
#pragma unroll
            for (int k = 0; k < DIM; ++k)
                v[k] += __shfl_xor(v[k], off);
        if ((threadIdx.x & 63) == 0) {
#pragma unroll
            for (int k = 0; k < DIM; ++k) atomicAdd(&sums[g0 * DIM + k], v[k]);
            atomicAdd(&cnt[g0], 64.f);
        }
    } else if (valid) {    // boundary wave (~63 of 1563)
#pragma unroll
        for (int k = 0; k < DIM; ++k) atomicAdd(&sums[g * DIM + k], v[k]);
        atomicAdd(&cnt[g], 1.f);
    }
}

// ---------------------------------------------------------------------------
// Kernel E: out[g] = sigmoid(((sums[g]/cnt[g]) @ W2) @ W3)
// (mean-pool commutes with the linear W2, folded here)
// ---------------------------------------------------------------------------
__global__ void k_final(const float* __restrict__ sums, const float* __restrict__ cnt,
                        const float* __restrict__ W2, const float* __restrict__ W3,
                        float* __restrict__ out) {
    int g = threadIdx.x;
    if (g >= NUM_GRAPHS) return;
    float c = fmaxf(cnt[g], 1.f);
    float p[DIM];
#pragma unroll
    for (int k = 0; k < DIM; ++k) p[k] = sums[g * DIM + k] / c;
    float z = 0.f;
#pragma unroll
    for (int j = 0; j < DIM; ++j) {
        float t = 0.f;
#pragma unroll
        for (int k = 0; k < DIM; ++k) t += p[k] * W2[k * DIM + j];
        z += t * W3[j];
    }
    out[g] = 1.f / (1.f + expf(-z));
}

// ---------------------------------------------------------------------------
// Workspace layout (bytes):
//   [0,         4000000)  h1    [100000,10] f32
//   [4000000,   8000000)  agg1
//   [8000000,  12000000)  agg2
//   [12000000, 12002560)  sums  [64,10]
//   [12002560, 12002816)  cnt   [64]
// ---------------------------------------------------------------------------
extern "C" void kernel_launch(void* const* d_in, const int* in_sizes, int n_in,
                              void* d_out, int out_size, void* d_ws, size_t ws_size,
                              hipStream_t stream) {
    const float* feat = (const float*)d_in[0];
    const float* W1   = (const float*)d_in[1];
    const float* W2   = (const float*)d_in[2];
    const float* W3   = (const float*)d_in[3];
    const int*   src  = (const int*)d_in[4];
    const int*   dst  = (const int*)d_in[5];
    const int*   gids = (const int*)d_in[6];
    float*       out  = (float*)d_out;

    char*  ws   = (char*)d_ws;
    float* h1   = (float*)(ws);
    float* agg1 = (float*)(ws + 4000000);
    float* agg2 = (float*)(ws + 8000000);
    float* sums = (float*)(ws + 12000000);
    float* cnt  = (float*)(ws + 12002560);

    // zero agg1, agg2, sums, cnt in one shot (ws is poisoned 0xAA each call)
    hipMemsetAsync(ws + 4000000, 0, 8002816, stream);

    k_gemm_w1<<<(N_NODES * 32 + 255) / 256, 256, 0, stream>>>(feat, W1, h1);
    k_edge_scatter<0><<<(N_EDGES + 255) / 256, 256, 0, stream>>>(h1, src, dst, agg1);
    k_edge_scatter<1><<<(N_EDGES + 255) / 256, 256, 0, stream>>>(agg1, src, dst, agg2);
    k_pool<<<(N_NODES + 255) / 256, 256, 0, stream>>>(agg2, gids, sums, cnt);
    k_final<<<1, 64, 0, stream>>>(sums, cnt, W2, W3, out);
}

// Round 2
// 720.380 us; speedup vs baseline: 4.7164x; 4.7164x over previous
//
#include <hip/hip_runtime.h>

#define N_NODES 100000
#define N_EDGES 3200000
#define NUM_FEATURES 128
#define DIM 10
#define NUM_GRAPHS 64
#define SCAN_BLOCKS 391   // ceil(100000/256)

// ---------------------------------------------------------------------------
// Kernel A: h1 = features @ W1   [100000,128] x [128,10]
// 32 lanes per node; lane l owns W1 rows 4l..4l+3 in registers; float4 feature
// loads are fully coalesced.
// ---------------------------------------------------------------------------
__global__ __launch_bounds__(256) void k_gemm_w1(const float* __restrict__ feat,
                                                 const float* __restrict__ W1,
                                                 float* __restrict__ h1) {
    int gid  = blockIdx.x * blockDim.x + threadIdx.x;
    int node = gid >> 5;
    int lane = gid & 31;
    if (node >= N_NODES) return;

    float w[4][DIM];
#pragma unroll
    for (int j = 0; j < 4; ++j)
#pragma unroll
        for (int k = 0; k < DIM; ++k)
            w[j][k] = W1[(lane * 4 + j) * DIM + k];

    const float4 f = *reinterpret_cast<const float4*>(feat + (size_t)node * NUM_FEATURES + lane * 4);
    float fv[4] = {f.x, f.y, f.z, f.w};

    float acc[DIM];
#pragma unroll
    for (int k = 0; k < DIM; ++k) acc[k] = 0.f;
#pragma unroll
    for (int j = 0; j < 4; ++j)
#pragma unroll
        for (int k = 0; k < DIM; ++k)
            acc[k] += fv[j] * w[j][k];

#pragma unroll
    for (int off = 16; off > 0; off >>= 1)
#pragma unroll
        for (int k = 0; k < DIM; ++k)
            acc[k] += __shfl_xor(acc[k], off);

    if (lane == 0) {
#pragma unroll
        for (int k = 0; k < DIM; ++k) h1[node * DIM + k] = acc[k];
    }
}

// ---------------------------------------------------------------------------
// CSR build: histogram -> scan -> placement
// ---------------------------------------------------------------------------
__global__ __launch_bounds__(256) void k_hist(const int* __restrict__ dst,
                                              int* __restrict__ deg) {
    int e = blockIdx.x * blockDim.x + threadIdx.x;
    if (e < N_EDGES) atomicAdd(&deg[dst[e]], 1);
}

// per-block inclusive scan of deg -> tmp; block totals -> bsum
__global__ __launch_bounds__(256) void k_scan1(const int* __restrict__ deg,
                                               int* __restrict__ tmp,
                                               int* __restrict__ bsum) {
    int i    = blockIdx.x * 256 + threadIdx.x;
    int lane = threadIdx.x & 63;
    int wave = threadIdx.x >> 6;
    int x    = (i < N_NODES) ? deg[i] : 0;
#pragma unroll
    for (int off = 1; off < 64; off <<= 1) {
        int t = __shfl_up(x, off);
        if (lane >= off) x += t;
    }
    __shared__ int wsum[4];
    if (lane == 63) wsum[wave] = x;
    __syncthreads();
    if (threadIdx.x == 0) {
        int s = 0;
#pragma unroll
        for (int w = 0; w < 4; ++w) { int t = wsum[w]; wsum[w] = s; s += t; }
        bsum[blockIdx.x] = s;
    }
    __syncthreads();
    x += wsum[wave];
    if (i < N_NODES) tmp[i] = x;
}

// exclusive scan of the 391 block sums (single block)
__global__ __launch_bounds__(512) void k_scan2(int* __restrict__ bsum,
                                               int* __restrict__ boff) {
    __shared__ int arr[SCAN_BLOCKS];
    int t = threadIdx.x;
    if (t < SCAN_BLOCKS) arr[t] = bsum[t];
    __syncthreads();
    if (t == 0) {
        int run = 0;
        for (int j = 0; j < SCAN_BLOCKS; ++j) { int v = arr[j]; arr[j] = run; run += v; }
    }
    __syncthreads();
    if (t < SCAN_BLOCKS) boff[t] = arr[t];
}

// finalize: row_ptr (exclusive bounds) + cursor copy for placement
__global__ __launch_bounds__(256) void k_scan3(const int* __restrict__ tmp,
                                               const int* __restrict__ boff,
                                               const int* __restrict__ deg,
                                               int* __restrict__ row_ptr,
                                               int* __restrict__ cursor) {
    int i = blockIdx.x * 256 + threadIdx.x;
    if (i >= N_NODES) return;
    int incl = tmp[i] + boff[blockIdx.x];
    row_ptr[i + 1] = incl;
    cursor[i]      = incl - deg[i];
    if (i == 0) row_ptr[0] = 0;
}

__global__ __launch_bounds__(256) void k_place(const int* __restrict__ src,
                                               const int* __restrict__ dst,
                                               int* __restrict__ cursor,
                                               int* __restrict__ csr_src) {
    int e = blockIdx.x * blockDim.x + threadIdx.x;
    if (e >= N_EDGES) return;
    int pos = atomicAdd(&cursor[dst[e]], 1);
    csr_src[pos] = src[e];
}

// ---------------------------------------------------------------------------
// Gather-aggregate: out[n][k] = sum_{e in row(n)} f(h[csr_src[e]][k])
// One wave per node: 6 edge-slots x 10 k-lanes (lanes 60-63 idle).
// Per edge: one broadcast idx load + one 40B coalesced vector read. No atomics.
// ---------------------------------------------------------------------------
template <int RELU>
__global__ __launch_bounds__(256) void k_gather(const float* __restrict__ h,
                                                const int* __restrict__ row_ptr,
                                                const int* __restrict__ csr_src,
                                                float* __restrict__ out) {
    int wave = threadIdx.x >> 6;
    int node = blockIdx.x * 4 + wave;
    if (node >= N_NODES) return;
    int lane = threadIdx.x & 63;
    int slot = lane / 10;        // 0..6 (slot 6 = lanes 60..63, idle)
    int k    = lane - slot * 10;

    int start = row_ptr[node];
    int end   = row_ptr[node + 1];

    float acc = 0.f;
    if (slot < 6) {
        for (int e = start + slot; e < end; e += 6) {
            int   s = csr_src[e];            // same addr across the 10 k-lanes
            float v = h[(size_t)s * DIM + k];
            acc += RELU ? fmaxf(v, 0.f) : v;
        }
    }
    // fold slots 3,4,5 into 0,1,2; then 1->0, 2->0
    acc += __shfl(acc, (lane + 30) & 63);
    acc += __shfl(acc, (lane + 10) & 63);
    acc += __shfl(acc, (lane + 20) & 63);
    if (lane < 10) out[(size_t)node * DIM + lane] = acc;
}

// ---------------------------------------------------------------------------
// Per-graph sums + counts (graph_ids sorted -> wave-uniform fast path)
// ---------------------------------------------------------------------------
__global__ __launch_bounds__(256) void k_pool(const float* __restrict__ agg2,
                                              const int* __restrict__ gids,
                                              float* __restrict__ sums,
                                              float* __restrict__ cnt) {
    int n      = blockIdx.x * blockDim.x + threadIdx.x;
    bool valid = (n < N_NODES);
    int g      = valid ? gids[n] : -1;

    float v[DIM];
#pragma unroll
    for (int k = 0; k < DIM; ++k)
        v[k] = valid ? agg2[(size_t)n * DIM + k] : 0.f;

    int  g0  = __shfl(g, 0);
    bool uni = __all(g == g0);

    if (uni && g0 >= 0) {
#pragma unroll
        for (int off = 32; off > 0; off >>= 1)
#pragma unroll
            for (int k = 0; k < DIM; ++k)
                v[k] += __shfl_xor(v[k], off);
        if ((threadIdx.x & 63) == 0) {
#pragma unroll
            for (int k = 0; k < DIM; ++k) atomicAdd(&sums[g0 * DIM + k], v[k]);
            atomicAdd(&cnt[g0], 64.f);
        }
    } else if (valid) {
#pragma unroll
        for (int k = 0; k < DIM; ++k) atomicAdd(&sums[g * DIM + k], v[k]);
        atomicAdd(&cnt[g], 1.f);
    }
}

__global__ void k_final(const float* __restrict__ sums, const float* __restrict__ cnt,
                        const float* __restrict__ W2, const float* __restrict__ W3,
                        float* __restrict__ out) {
    int g = threadIdx.x;
    if (g >= NUM_GRAPHS) return;
    float c = fmaxf(cnt[g], 1.f);
    float p[DIM];
#pragma unroll
    for (int k = 0; k < DIM; ++k) p[k] = sums[g * DIM + k] / c;
    float z = 0.f;
#pragma unroll
    for (int j = 0; j < DIM; ++j) {
        float t = 0.f;
#pragma unroll
        for (int k = 0; k < DIM; ++k) t += p[k] * W2[k * DIM + j];
        z += t * W3[j];
    }
    out[g] = 1.f / (1.f + expf(-z));
}

// ---------------------------------------------------------------------------
// Workspace layout (bytes, 4B-aligned):
//   h1      [0,        4000000)
//   agg1    [4000000,  8000000)
//   agg2    [8000000, 12000000)
//   csr_src [12000000, 24800000)   3.2M int
//   deg     [24800000, 25200000)   100k int   <- zeroed
//   tmp     [25200000, 25600000)
//   row_ptr [25600000, 26000004)   100001 int
//   cursor  [26000004, 26400004)
//   bsum    [26400004, 26401568)   391 int
//   boff    [26401568, 26403132)
//   sums    [26403132, 26405692)   64x10 f32  <- zeroed
//   cnt     [26405692, 26405948)   64 f32     <- zeroed
// ---------------------------------------------------------------------------
extern "C" void kernel_launch(void* const* d_in, const int* in_sizes, int n_in,
                              void* d_out, int out_size, void* d_ws, size_t ws_size,
                              hipStream_t stream) {
    const float* feat = (const float*)d_in[0];
    const float* W1   = (const float*)d_in[1];
    const float* W2   = (const float*)d_in[2];
    const float* W3   = (const float*)d_in[3];
    const int*   src  = (const int*)d_in[4];
    const int*   dst  = (const int*)d_in[5];
    const int*   gids = (const int*)d_in[6];
    float*       out  = (float*)d_out;

    char* ws = (char*)d_ws;
    float* h1      = (float*)(ws);
    float* agg1    = (float*)(ws + 4000000);
    float* agg2    = (float*)(ws + 8000000);
    int*   csr_src = (int*)(ws + 12000000);
    int*   deg     = (int*)(ws + 24800000);
    int*   tmp     = (int*)(ws + 25200000);
    int*   row_ptr = (int*)(ws + 25600000);
    int*   cursor  = (int*)(ws + 26000004);
    int*   bsum    = (int*)(ws + 26400004);
    int*   boff    = (int*)(ws + 26401568);
    float* sums    = (float*)(ws + 26403132);
    float* cnt     = (float*)(ws + 26405692);

    // zero: deg (400 KB) and sums+cnt (2816 B)
    hipMemsetAsync(deg, 0, 400000, stream);
    hipMemsetAsync(sums, 0, 2816, stream);

    const int EB = (N_EDGES + 255) / 256;

    k_gemm_w1<<<(N_NODES * 32 + 255) / 256, 256, 0, stream>>>(feat, W1, h1);
    k_hist  <<<EB, 256, 0, stream>>>(dst, deg);
    k_scan1 <<<SCAN_BLOCKS, 256, 0, stream>>>(deg, tmp, bsum);
    k_scan2 <<<1, 512, 0, stream>>>(bsum, boff);
    k_scan3 <<<SCAN_BLOCKS, 256, 0, stream>>>(tmp, boff, deg, row_ptr, cursor);
    k_place <<<EB, 256, 0, stream>>>(src, dst, cursor, csr_src);

    k_gather<0><<<(N_NODES + 3) / 4, 256, 0, stream>>>(h1,   row_ptr, csr_src, agg1);
    k_gather<1><<<(N_NODES + 3) / 4, 256, 0, stream>>>(agg1, row_ptr, csr_src, agg2);

    k_pool <<<(N_NODES + 255) / 256, 256, 0, stream>>>(agg2, gids, sums, cnt);
    k_final<<<1, 64, 0, stream>>>(sums, cnt, W2, W3, out);
}

// Round 3
// 679.412 us; speedup vs baseline: 5.0008x; 1.0603x over previous
//
#include <hip/hip_runtime.h>

#define N_NODES 100000
#define N_EDGES 3200000
#define NUM_FEATURES 128
#define DIM 10
#define NUM_GRAPHS 64

#define BSHIFT 8                         // 256 nodes per bucket
#define BSIZE (1 << BSHIFT)
#define NB ((N_NODES + BSIZE - 1) / BSIZE)   // 391 buckets
#define EPB 8192                         // edges per block in hist/place
#define EBLOCKS ((N_EDGES + EPB - 1) / EPB)  // 391

// ---------------------------------------------------------------------------
// Kernel A: h1 = features @ W1   [100000,128] x [128,10]
// 32 lanes/node, W1 in registers, float4 coalesced feature reads.
// ---------------------------------------------------------------------------
__global__ __launch_bounds__(256) void k_gemm_w1(const float* __restrict__ feat,
                                                 const float* __restrict__ W1,
                                                 float* __restrict__ h1) {
    int gid  = blockIdx.x * blockDim.x + threadIdx.x;
    int node = gid >> 5;
    int lane = gid & 31;
    if (node >= N_NODES) return;

    float w[4][DIM];
#pragma unroll
    for (int j = 0; j < 4; ++j)
#pragma unroll
        for (int k = 0; k < DIM; ++k)
            w[j][k] = W1[(lane * 4 + j) * DIM + k];

    const float4 f = *reinterpret_cast<const float4*>(feat + (size_t)node * NUM_FEATURES + lane * 4);
    float fv[4] = {f.x, f.y, f.z, f.w};

    float acc[DIM];
#pragma unroll
    for (int k = 0; k < DIM; ++k) acc[k] = 0.f;
#pragma unroll
    for (int j = 0; j < 4; ++j)
#pragma unroll
        for (int k = 0; k < DIM; ++k)
            acc[k] += fv[j] * w[j][k];

#pragma unroll
    for (int off = 16; off > 0; off >>= 1)
#pragma unroll
        for (int k = 0; k < DIM; ++k)
            acc[k] += __shfl_xor(acc[k], off);

    if (lane == 0) {
#pragma unroll
        for (int k = 0; k < DIM; ++k) h1[node * DIM + k] = acc[k];
    }
}

// ---------------------------------------------------------------------------
// Bucket histogram: LDS per-block hist over 391 bins, one global atomic/bin.
// ---------------------------------------------------------------------------
__global__ __launch_bounds__(512) void k_bhist(const int* __restrict__ dst,
                                               int* __restrict__ bcnt) {
    __shared__ int h[NB];
    for (int t = threadIdx.x; t < NB; t += 512) h[t] = 0;
    __syncthreads();
    int base = blockIdx.x * EPB;
    int end  = min(base + EPB, N_EDGES);
    for (int i = base + threadIdx.x; i < end; i += 512)
        atomicAdd(&h[dst[i] >> BSHIFT], 1);
    __syncthreads();
    for (int t = threadIdx.x; t < NB; t += 512)
        if (h[t]) atomicAdd(&bcnt[t], h[t]);
}

// exclusive scan of 391 bins -> bstart[NB+1], cursor copy
__global__ void k_bscan(const int* __restrict__ bcnt,
                        int* __restrict__ bstart,
                        int* __restrict__ cursor) {
    if (threadIdx.x == 0) {
        int run = 0;
        for (int b = 0; b < NB; ++b) {
            bstart[b] = run;
            cursor[b] = run;
            run += bcnt[b];
        }
        bstart[NB] = run;
    }
}

// ---------------------------------------------------------------------------
// Bucket placement: LDS hist -> one global atomic reservation per (block,bin)
// -> LDS-cursor scatter of packed edges: (dst&255)<<17 | src  (26 bits).
// ---------------------------------------------------------------------------
__global__ __launch_bounds__(512) void k_bplace(const int* __restrict__ src,
                                                const int* __restrict__ dst,
                                                int* __restrict__ cursor,
                                                int* __restrict__ pk) {
    __shared__ int h[NB];
    for (int t = threadIdx.x; t < NB; t += 512) h[t] = 0;
    __syncthreads();
    int base = blockIdx.x * EPB;
    int end  = min(base + EPB, N_EDGES);
    for (int i = base + threadIdx.x; i < end; i += 512)
        atomicAdd(&h[dst[i] >> BSHIFT], 1);
    __syncthreads();
    // reserve contiguous run per bin; h[t] becomes the local write cursor
    for (int t = threadIdx.x; t < NB; t += 512) {
        int c = h[t];
        h[t] = c ? atomicAdd(&cursor[t], c) : 0;
    }
    __syncthreads();
    for (int i = base + threadIdx.x; i < end; i += 512) {
        int d   = dst[i];                 // L2-hot re-read
        int s   = src[i];
        int bin = d >> BSHIFT;
        int pos = atomicAdd(&h[bin], 1);
        pk[pos] = ((d & (BSIZE - 1)) << 17) | s;
    }
}

// ---------------------------------------------------------------------------
// Bucketed SpMM: one block per bucket; 256x10 f32 accumulator in LDS.
// 6 edge-slots x 10 k-lanes per wave; per edge: 4B packed load (broadcast),
// 40B gather of h[src], 10 LDS f32 atomic adds. Coalesced epilogue store.
// ---------------------------------------------------------------------------
template <int RELU>
__global__ __launch_bounds__(512) void k_spmm(const float* __restrict__ h,
                                              const int* __restrict__ bstart,
                                              const int* __restrict__ pk,
                                              float* __restrict__ outp) {
    __shared__ float acc[BSIZE * DIM];
    for (int t = threadIdx.x; t < BSIZE * DIM; t += 512) acc[t] = 0.f;
    __syncthreads();

    int b  = blockIdx.x;
    int s0 = bstart[b];
    int s1 = bstart[b + 1];

    int wave = threadIdx.x >> 6;
    int lane = threadIdx.x & 63;
    int slot = lane / 10;          // 0..6 (6 = idle lanes 60..63)
    int k    = lane - slot * 10;

    if (slot < 6) {
        for (int e = s0 + wave * 6 + slot; e < s1; e += 48) {
            int   p   = pk[e];
            int   s   = p & 0x1FFFF;
            int   loc = p >> 17;
            float v   = h[(size_t)s * DIM + k];
            if (RELU) v = fmaxf(v, 0.f);
            atomicAdd(&acc[loc * DIM + k], v);
        }
    }
    __syncthreads();

    int nbase = b << BSHIFT;
    for (int t = threadIdx.x; t < BSIZE * DIM; t += 512) {
        int node = nbase + t / DIM;
        if (node < N_NODES) outp[(size_t)node * DIM + t % DIM] = acc[t];
    }
}

// ---------------------------------------------------------------------------
// Per-graph sums + counts (graph_ids sorted -> wave-uniform fast path)
// ---------------------------------------------------------------------------
__global__ __launch_bounds__(256) void k_pool(const float* __restrict__ agg2,
                                              const int* __restrict__ gids,
                                              float* __restrict__ sums,
                                              float* __restrict__ cnt) {
    int n      = blockIdx.x * blockDim.x + threadIdx.x;
    bool valid = (n < N_NODES);
    int g      = valid ? gids[n] : -1;

    float v[DIM];
#pragma unroll
    for (int k = 0; k < DIM; ++k)
        v[k] = valid ? agg2[(size_t)n * DIM + k] : 0.f;

    int  g0  = __shfl(g, 0);
    bool uni = __all(g == g0);

    if (uni && g0 >= 0) {
#pragma unroll
        for (int off = 32; off > 0; off >>= 1)
#pragma unroll
            for (int k = 0; k < DIM; ++k)
                v[k] += __shfl_xor(v[k], off);
        if ((threadIdx.x & 63) == 0) {
#pragma unroll
            for (int k = 0; k < DIM; ++k) atomicAdd(&sums[g0 * DIM + k], v[k]);
            atomicAdd(&cnt[g0], 64.f);
        }
    } else if (valid) {
#pragma unroll
        for (int k = 0; k < DIM; ++k) atomicAdd(&sums[g * DIM + k], v[k]);
        atomicAdd(&cnt[g], 1.f);
    }
}

__global__ void k_final(const float* __restrict__ sums, const float* __restrict__ cnt,
                        const float* __restrict__ W2, const float* __restrict__ W3,
                        float* __restrict__ out) {
    int g = threadIdx.x;
    if (g >= NUM_GRAPHS) return;
    float c = fmaxf(cnt[g], 1.f);
    float p[DIM];
#pragma unroll
    for (int k = 0; k < DIM; ++k) p[k] = sums[g * DIM + k] / c;
    float z = 0.f;
#pragma unroll
    for (int j = 0; j < DIM; ++j) {
        float t = 0.f;
#pragma unroll
        for (int k = 0; k < DIM; ++k) t += p[k] * W2[k * DIM + j];
        z += t * W3[j];
    }
    out[g] = 1.f / (1.f + expf(-z));
}

// ---------------------------------------------------------------------------
// Workspace layout (bytes):
//   h1       [0,         4000000)
//   agg1     [4000000,   8000000)
//   agg2     [8000000,  12000000)
//   pk       [12000000, 24800000)   3.2M packed edges
//   bcnt     [24800000, 24801600)   391 int (pad)  <- zeroed
//   sums     [24801600, 24804160)   64x10 f32      <- zeroed
//   cnt      [24804160, 24804416)   64 f32         <- zeroed
//   bstart   [24804416, 24805984)   392 int
//   cursor   [24805984, 24807548)   391 int
// ---------------------------------------------------------------------------
extern "C" void kernel_launch(void* const* d_in, const int* in_sizes, int n_in,
                              void* d_out, int out_size, void* d_ws, size_t ws_size,
                              hipStream_t stream) {
    const float* feat = (const float*)d_in[0];
    const float* W1   = (const float*)d_in[1];
    const float* W2   = (const float*)d_in[2];
    const float* W3   = (const float*)d_in[3];
    const int*   src  = (const int*)d_in[4];
    const int*   dst  = (const int*)d_in[5];
    const int*   gids = (const int*)d_in[6];
    float*       out  = (float*)d_out;

    char* ws = (char*)d_ws;
    float* h1     = (float*)(ws);
    float* agg1   = (float*)(ws + 4000000);
    float* agg2   = (float*)(ws + 8000000);
    int*   pk     = (int*)(ws + 12000000);
    int*   bcnt   = (int*)(ws + 24800000);
    float* sums   = (float*)(ws + 24801600);
    float* cnt    = (float*)(ws + 24804160);
    int*   bstart = (int*)(ws + 24804416);
    int*   cursor = (int*)(ws + 24805984);

    // zero bcnt + sums + cnt in one shot
    hipMemsetAsync(ws + 24800000, 0, 4416, stream);

    k_gemm_w1<<<(N_NODES * 32 + 255) / 256, 256, 0, stream>>>(feat, W1, h1);
    k_bhist <<<EBLOCKS, 512, 0, stream>>>(dst, bcnt);
    k_bscan <<<1, 64, 0, stream>>>(bcnt, bstart, cursor);
    k_bplace<<<EBLOCKS, 512, 0, stream>>>(src, dst, cursor, pk);

    k_spmm<0><<<NB, 512, 0, stream>>>(h1,   bstart, pk, agg1);
    k_spmm<1><<<NB, 512, 0, stream>>>(agg1, bstart, pk, agg2);

    k_pool <<<(N_NODES + 255) / 256, 256, 0, stream>>>(agg2, gids, sums, cnt);
    k_final<<<1, 64, 0, stream>>>(sums, cnt, W2, W3, out);
}